// Round 2
// baseline (196.766 us; speedup 1.0000x reference)
//
#include <hip/hip_runtime.h>

typedef __attribute__((ext_vector_type(8))) short short8;
typedef __attribute__((ext_vector_type(4))) float float4v;

__device__ __forceinline__ unsigned short f2bf(float f) {
    unsigned u = __float_as_uint(f);
    u = (u + 0x7FFFu + ((u >> 16) & 1u)) >> 16;
    return (unsigned short)u;
}

#define XSET 520   // 512 data + 8 pad ushorts per (g,ks) fragment set
#define CROW 68    // 64 px + 4 pad floats per staged C row
#define SMEM_BYTES 34816   // single aliased region: x frags / z frags / C staging

// ---------------------------------------------------------------------------
// Prepack: W1 [256x64], W2 [96x256] ([cin,cout]) -> bf16 MFMA A-frag order.
// A[m][k]: m = lane&15, k = (lane>>4)*8 + j.
// A1: ((mt*8 + ks)*64 + lane)*8 + j   (mt 0..3,  ks 0..7)
// A2: ((mt*3 + ks)*64 + lane)*8 + j   (mt 0..15, ks 0..2)
// ---------------------------------------------------------------------------
__global__ void prepack(const float* __restrict__ W1_0, const float* __restrict__ W2_0,
                        const float* __restrict__ W1_1, const float* __restrict__ W2_1,
                        const float* __restrict__ W1_2, const float* __restrict__ W2_2,
                        unsigned short* __restrict__ ws) {
    int e = blockIdx.x * 256 + threadIdx.x;
    if (e >= 3 * 40960) return;
    int l = e / 40960, r = e % 40960;
    const float* W1 = (l == 0) ? W1_0 : (l == 1) ? W1_1 : W1_2;
    const float* W2 = (l == 0) ? W2_0 : (l == 1) ? W2_1 : W2_2;
    unsigned short* base = ws + l * 40960;
    if (r < 16384) {
        int j = r & 7, lane = (r >> 3) & 63, fs = r >> 9;
        int mt = fs >> 3, ks = fs & 7;
        int k = ks * 32 + (lane >> 4) * 8 + j;
        int m = mt * 16 + (lane & 15);
        base[r] = f2bf(W1[k * 64 + m]);
    } else {
        int r2 = r - 16384;
        int j = r2 & 7, lane = (r2 >> 3) & 63, fs = r2 >> 9;
        int mt = fs / 3, ks = fs - mt * 3;
        int k = ks * 32 + (lane >> 4) * 8 + j;
        int m = mt * 16 + (lane & 15);
        base[16384 + r2] = f2bf(W2[k * 256 + m]);
    }
}

// ---------------------------------------------------------------------------
// Block = 256 thr (4 waves) = 64 px, all channels. All global I/O in >=256 B
// contiguous runs. One 34816 B LDS region, time-multiplexed:
//   [phase1]  x frags (33312 B incl. per-g skew)      writes
//   [stage1]  x frags read -> BARRIER -> z frags (12480 B, aliases x) writes
//   [stage2]  z frags read -> BARRIER -> C staging (34816 B, aliases all)
// 34816 B -> 4 blocks/CU (was 47616 -> 3).
// ---------------------------------------------------------------------------
template<int HW>
__device__ __forceinline__ void level3(
    const float* __restrict__ x,           // this batch: [256][HW]
    const unsigned short* __restrict__ A1,
    const unsigned short* __restrict__ A2,
    const float* __restrict__ b1, const float* __restrict__ b2,
    float* __restrict__ o, int px0,
    unsigned short* __restrict__ xs)       // 34816 B shared region
{
    const int t = (int)threadIdx.x;
    const int lane = t & 63, w = t >> 6;
    const int q = lane >> 4, n = lane & 15;
    unsigned short* zs = xs;               // z frags alias x region (barriered)

    // ---- phase 1: stage x [256 ch][64 px] -> bf16 frag layout in LDS ----
    // All 16 strided float4 loads issued before any convert/store: one HBM
    // latency round instead of ~4 (VGPR budget 128 with launch_bounds(256,4)).
    {
        const int ch_lo = t >> 4;               // 0..15
        const int pp = t & 15;                  // px = 4*pp + e
        const int g = pp >> 2;
        const int n0 = (pp & 3) * 4;
        const float* xp = x + (size_t)ch_lo * HW + px0 + 4 * pp;
        float4v v[16];
#pragma unroll
        for (int i = 0; i < 16; ++i)
            v[i] = *(const float4v*)(xp + (size_t)(i * 16) * HW);
#pragma unroll
        for (int i = 0; i < 16; ++i) {
            const int ch = i * 16 + ch_lo;
            const int ks = ch >> 5, qq = (ch >> 3) & 3, j = ch & 7;
            // +g*8 ushort (16 B) skew: breaks the g*2080-word (== 0 mod 32
            // banks) degeneracy of the staging writes -> 4x more banks hit.
            unsigned short* base = xs + (g * 8 + ks) * XSET + g * 8 + j;
#pragma unroll
            for (int e = 0; e < 4; ++e)
                base[(qq * 16 + n0 + e) * 8] = f2bf(v[i][e]);
        }
    }
    __syncthreads();

    // ---- stage 1: wave w -> px group g = w ----
    float4v acc1[4];
#pragma unroll
    for (int mt = 0; mt < 4; ++mt)
        acc1[mt] = *(const float4v*)(b1 + mt * 16 + q * 4);

    short8 xf[8];
#pragma unroll
    for (int ks = 0; ks < 8; ++ks)
        xf[ks] = *(const short8*)(xs + (w * 8 + ks) * XSET + w * 8 + lane * 8);
    // all waves must have consumed x frags before z overwrites the region
    __syncthreads();

    const short8* A1f = (const short8*)A1;
#pragma unroll
    for (int ks = 0; ks < 8; ++ks)
#pragma unroll
        for (int mt = 0; mt < 4; ++mt)
            acc1[mt] = __builtin_amdgcn_mfma_f32_16x16x32_bf16(
                A1f[(mt * 8 + ks) * 64 + lane], xf[ks], acc1[mt], 0, 0, 0);

    // ---- z = [y, relu(y_hi)] -> shared frag-layout LDS (b64 packed) ----
    {
        unsigned short* zg = zs + w * 3 * XSET;
#pragma unroll
        for (int mt = 0; mt < 4; ++mt) {
            const int kb = mt * 16 + q * 4;   // C row = q*4+r = ch kb+r
            unsigned long long pk =
                  (unsigned long long)f2bf(acc1[mt][0])
                | ((unsigned long long)f2bf(acc1[mt][1]) << 16)
                | ((unsigned long long)f2bf(acc1[mt][2]) << 32)
                | ((unsigned long long)f2bf(acc1[mt][3]) << 48);
            *(unsigned long long*)(zg + (kb >> 5) * XSET +
                (((kb >> 3) & 3) * 16 + n) * 8 + (kb & 7)) = pk;
            if (mt >= 2) {
                const int kr = kb + 32;       // relu copy at k = 64 + (ch-32)
                unsigned long long pr =
                      (unsigned long long)f2bf(fmaxf(acc1[mt][0], 0.f))
                    | ((unsigned long long)f2bf(fmaxf(acc1[mt][1], 0.f)) << 16)
                    | ((unsigned long long)f2bf(fmaxf(acc1[mt][2], 0.f)) << 32)
                    | ((unsigned long long)f2bf(fmaxf(acc1[mt][3], 0.f)) << 48);
                *(unsigned long long*)(zg + (kr >> 5) * XSET +
                    (((kr >> 3) & 3) * 16 + n) * 8 + (kr & 7)) = pr;
            }
        }
    }
    __syncthreads();

    // ---- stage 2: wave w -> out-ch 64w..64w+63, all 4 px groups ----
    float4v acc2[4][4];   // [mm][g]
#pragma unroll
    for (int mm = 0; mm < 4; ++mm) {
        float4v bb = *(const float4v*)(b2 + (w * 4 + mm) * 16 + q * 4);
#pragma unroll
        for (int g = 0; g < 4; ++g) acc2[mm][g] = bb;
    }

    const short8* A2f = (const short8*)A2;
#pragma unroll
    for (int g = 0; g < 4; ++g) {
        short8 zf[3];
#pragma unroll
        for (int ks = 0; ks < 3; ++ks)
            zf[ks] = *(const short8*)(zs + (g * 3 + ks) * XSET + lane * 8);
#pragma unroll
        for (int ks = 0; ks < 3; ++ks)
#pragma unroll
            for (int mm = 0; mm < 4; ++mm)
                acc2[mm][g] = __builtin_amdgcn_mfma_f32_16x16x32_bf16(
                    A2f[((w * 4 + mm) * 3 + ks) * 64 + lane], zf[ks], acc2[mm][g], 0, 0, 0);
    }
    // all z reads done before C staging overwrites the region
    __syncthreads();

    // ---- store: C -> LDS (wave-private slot) -> px-major nt dwordx4 ----
    float* cw = (float*)xs + w * 32 * CROW;   // aliases region (post-barrier)
#pragma unroll
    for (int p = 0; p < 2; ++p) {
#pragma unroll
        for (int mp = 0; mp < 2; ++mp) {
            const int mm = p * 2 + mp;
#pragma unroll
            for (int g = 0; g < 4; ++g)
#pragma unroll
                for (int r = 0; r < 4; ++r)
                    cw[(mp * 16 + q * 4 + r) * CROW + g * 16 + n] = acc2[mm][g][r];
        }
        // wave-private slot: DS ops from one wave execute in order; no barrier
        const int chs = lane >> 4;            // 0..3
        const int pp = lane & 15;
        float* op = o + (size_t)(w * 64 + p * 32 + chs) * HW + px0 + 4 * pp;
#pragma unroll
        for (int i = 0; i < 8; ++i) {
            float4v v = *(const float4v*)(cw + (i * 4 + chs) * CROW + 4 * pp);
            __builtin_nontemporal_store(v, (float4v*)(op + (size_t)(i * 4) * HW));
        }
    }
}

__global__ __launch_bounds__(256, 4) void fused_v5(
    const float* __restrict__ x0, const float* __restrict__ x1, const float* __restrict__ x2,
    const float* __restrict__ b1_0, const float* __restrict__ b2_0,
    const float* __restrict__ b1_1, const float* __restrict__ b2_1,
    const float* __restrict__ b1_2, const float* __restrict__ b2_2,
    const unsigned short* __restrict__ wpk, float* __restrict__ out)
{
    __shared__ __align__(16) unsigned char smem[SMEM_BYTES];
    unsigned short* xs = (unsigned short*)smem;
    const int bi = (int)blockIdx.x;

    if (bi < 1024) {                        // level 0: 4 batches x 256 tiles
        int b = bi >> 8, px0 = (bi & 255) * 64;
        level3<16384>(x0 + (size_t)b * 256 * 16384, wpk, wpk + 16384, b1_0, b2_0,
                      out + (size_t)b * 256 * 16384, px0, xs);
    } else if (bi < 1280) {                 // level 1: 4 x 64 tiles
        int r = bi - 1024, b = r >> 6, px0 = (r & 63) * 64;
        level3<4096>(x1 + (size_t)b * 256 * 4096, wpk + 40960, wpk + 40960 + 16384,
                     b1_1, b2_1, out + 16777216 + (size_t)b * 256 * 4096, px0, xs);
    } else {                                // level 2: 4 x 16 tiles
        int r = bi - 1280, b = r >> 4, px0 = (r & 15) * 64;
        level3<1024>(x2 + (size_t)b * 256 * 1024, wpk + 81920, wpk + 81920 + 16384,
                     b1_2, b2_2, out + 20971520 + (size_t)b * 256 * 1024, px0, xs);
    }
}

extern "C" void kernel_launch(void* const* d_in, const int* in_sizes, int n_in,
                              void* d_out, int out_size, void* d_ws, size_t ws_size,
                              hipStream_t stream) {
    const float* x0   = (const float*)d_in[0];
    const float* x1   = (const float*)d_in[1];
    const float* x2   = (const float*)d_in[2];
    const float* W1_0 = (const float*)d_in[3];
    const float* b1_0 = (const float*)d_in[4];
    const float* W2_0 = (const float*)d_in[5];
    const float* b2_0 = (const float*)d_in[6];
    const float* W1_1 = (const float*)d_in[7];
    const float* b1_1 = (const float*)d_in[8];
    const float* W2_1 = (const float*)d_in[9];
    const float* b2_1 = (const float*)d_in[10];
    const float* W1_2 = (const float*)d_in[11];
    const float* b1_2 = (const float*)d_in[12];
    const float* W2_2 = (const float*)d_in[13];
    const float* b2_2 = (const float*)d_in[14];
    float* out = (float*)d_out;
    unsigned short* wpk = (unsigned short*)d_ws;   // needs 245760 B

    prepack<<<dim3(480), dim3(256), 0, stream>>>(W1_0, W2_0, W1_1, W2_1, W1_2, W2_2, wpk);
    fused_v5<<<dim3(1344), dim3(256), 0, stream>>>(
        x0, x1, x2, b1_0, b2_0, b1_1, b2_1, b1_2, b2_2, wpk, out);
}

// Round 3
// 195.263 us; speedup vs baseline: 1.0077x; 1.0077x over previous
//
#include <hip/hip_runtime.h>

typedef __attribute__((ext_vector_type(8))) short short8;
typedef __attribute__((ext_vector_type(4))) float float4v;

__device__ __forceinline__ unsigned short f2bf(float f) {
    unsigned u = __float_as_uint(f);
    u = (u + 0x7FFFu + ((u >> 16) & 1u)) >> 16;
    return (unsigned short)u;
}

#define XSET 520   // 512 data + 8 pad ushorts per (g,ks) fragment set
#define CROW 68    // 64 px + 4 pad floats per staged C row
#define SMEM_BYTES 34816   // single aliased region: x frags / z frags / C staging

// ---------------------------------------------------------------------------
// Prepack: W1 [256x64], W2 [96x256] ([cin,cout]) -> bf16 MFMA A-frag order.
// A[m][k]: m = lane&15, k = (lane>>4)*8 + j.
// A1: ((mt*8 + ks)*64 + lane)*8 + j   (mt 0..3,  ks 0..7)
// A2: ((mt*3 + ks)*64 + lane)*8 + j   (mt 0..15, ks 0..2)
// ---------------------------------------------------------------------------
__global__ void prepack(const float* __restrict__ W1_0, const float* __restrict__ W2_0,
                        const float* __restrict__ W1_1, const float* __restrict__ W2_1,
                        const float* __restrict__ W1_2, const float* __restrict__ W2_2,
                        unsigned short* __restrict__ ws) {
    int e = blockIdx.x * 256 + threadIdx.x;
    if (e >= 3 * 40960) return;
    int l = e / 40960, r = e % 40960;
    const float* W1 = (l == 0) ? W1_0 : (l == 1) ? W1_1 : W1_2;
    const float* W2 = (l == 0) ? W2_0 : (l == 1) ? W2_1 : W2_2;
    unsigned short* base = ws + l * 40960;
    if (r < 16384) {
        int j = r & 7, lane = (r >> 3) & 63, fs = r >> 9;
        int mt = fs >> 3, ks = fs & 7;
        int k = ks * 32 + (lane >> 4) * 8 + j;
        int m = mt * 16 + (lane & 15);
        base[r] = f2bf(W1[k * 64 + m]);
    } else {
        int r2 = r - 16384;
        int j = r2 & 7, lane = (r2 >> 3) & 63, fs = r2 >> 9;
        int mt = fs / 3, ks = fs - mt * 3;
        int k = ks * 32 + (lane >> 4) * 8 + j;
        int m = mt * 16 + (lane & 15);
        base[16384 + r2] = f2bf(W2[k * 256 + m]);
    }
}

// ---------------------------------------------------------------------------
// Block = 256 thr (4 waves) = 64 px, all channels. All global I/O in >=256 B
// contiguous runs. One 34816 B LDS region, time-multiplexed:
//   [phase1]  x frags (33312 B incl. per-g skew)      writes
//   [stage1]  x frags read -> BARRIER -> z frags (12480 B, aliases x) writes
//   [stage2]  z frags read -> BARRIER -> C staging (34816 B, aliases all)
// Stores are PLAIN (not nontemporal): out (88 MB) + x (88 MB) fit the 256 MB
// L3 together; NT bypass forced scattered 256 B chunks straight to DRAM rows
// (the occupancy-independent 60 us floor of v3/v5).
// ---------------------------------------------------------------------------
template<int HW>
__device__ __forceinline__ void level3(
    const float* __restrict__ x,           // this batch: [256][HW]
    const unsigned short* __restrict__ A1,
    const unsigned short* __restrict__ A2,
    const float* __restrict__ b1, const float* __restrict__ b2,
    float* __restrict__ o, int px0,
    unsigned short* __restrict__ xs)       // 34816 B shared region
{
    const int t = (int)threadIdx.x;
    const int lane = t & 63, w = t >> 6;
    const int q = lane >> 4, n = lane & 15;
    unsigned short* zs = xs;               // z frags alias x region (barriered)

    // ---- phase 1: stage x [256 ch][64 px] -> bf16 frag layout in LDS ----
    {
        const int ch_lo = t >> 4;               // 0..15
        const int pp = t & 15;                  // px = 4*pp + e
        const int g = pp >> 2;
        const int n0 = (pp & 3) * 4;
        const float* xp = x + (size_t)ch_lo * HW + px0 + 4 * pp;
        float4v v[16];
#pragma unroll
        for (int i = 0; i < 16; ++i)
            v[i] = *(const float4v*)(xp + (size_t)(i * 16) * HW);
#pragma unroll
        for (int i = 0; i < 16; ++i) {
            const int ch = i * 16 + ch_lo;
            const int ks = ch >> 5, qq = (ch >> 3) & 3, j = ch & 7;
            // +g*8 ushort (16 B) skew: breaks the g*2080-word (== 0 mod 32
            // banks) degeneracy of the staging writes.
            unsigned short* base = xs + (g * 8 + ks) * XSET + g * 8 + j;
#pragma unroll
            for (int e = 0; e < 4; ++e)
                base[(qq * 16 + n0 + e) * 8] = f2bf(v[i][e]);
        }
    }
    __syncthreads();

    // ---- stage 1: wave w -> px group g = w ----
    float4v acc1[4];
#pragma unroll
    for (int mt = 0; mt < 4; ++mt)
        acc1[mt] = *(const float4v*)(b1 + mt * 16 + q * 4);

    short8 xf[8];
#pragma unroll
    for (int ks = 0; ks < 8; ++ks)
        xf[ks] = *(const short8*)(xs + (w * 8 + ks) * XSET + w * 8 + lane * 8);
    // all waves must have consumed x frags before z overwrites the region
    __syncthreads();

    const short8* A1f = (const short8*)A1;
#pragma unroll
    for (int ks = 0; ks < 8; ++ks)
#pragma unroll
        for (int mt = 0; mt < 4; ++mt)
            acc1[mt] = __builtin_amdgcn_mfma_f32_16x16x32_bf16(
                A1f[(mt * 8 + ks) * 64 + lane], xf[ks], acc1[mt], 0, 0, 0);

    // ---- z = [y, relu(y_hi)] -> shared frag-layout LDS (b64 packed) ----
    {
        unsigned short* zg = zs + w * 3 * XSET;
#pragma unroll
        for (int mt = 0; mt < 4; ++mt) {
            const int kb = mt * 16 + q * 4;   // C row = q*4+r = ch kb+r
            unsigned long long pk =
                  (unsigned long long)f2bf(acc1[mt][0])
                | ((unsigned long long)f2bf(acc1[mt][1]) << 16)
                | ((unsigned long long)f2bf(acc1[mt][2]) << 32)
                | ((unsigned long long)f2bf(acc1[mt][3]) << 48);
            *(unsigned long long*)(zg + (kb >> 5) * XSET +
                (((kb >> 3) & 3) * 16 + n) * 8 + (kb & 7)) = pk;
            if (mt >= 2) {
                const int kr = kb + 32;       // relu copy at k = 64 + (ch-32)
                unsigned long long pr =
                      (unsigned long long)f2bf(fmaxf(acc1[mt][0], 0.f))
                    | ((unsigned long long)f2bf(fmaxf(acc1[mt][1], 0.f)) << 16)
                    | ((unsigned long long)f2bf(fmaxf(acc1[mt][2], 0.f)) << 32)
                    | ((unsigned long long)f2bf(fmaxf(acc1[mt][3], 0.f)) << 48);
                *(unsigned long long*)(zg + (kr >> 5) * XSET +
                    (((kr >> 3) & 3) * 16 + n) * 8 + (kr & 7)) = pr;
            }
        }
    }
    __syncthreads();

    // ---- stage 2: wave w -> out-ch 64w..64w+63, all 4 px groups ----
    float4v acc2[4][4];   // [mm][g]
#pragma unroll
    for (int mm = 0; mm < 4; ++mm) {
        float4v bb = *(const float4v*)(b2 + (w * 4 + mm) * 16 + q * 4);
#pragma unroll
        for (int g = 0; g < 4; ++g) acc2[mm][g] = bb;
    }

    const short8* A2f = (const short8*)A2;
#pragma unroll
    for (int g = 0; g < 4; ++g) {
        short8 zf[3];
#pragma unroll
        for (int ks = 0; ks < 3; ++ks)
            zf[ks] = *(const short8*)(zs + (g * 3 + ks) * XSET + lane * 8);
#pragma unroll
        for (int ks = 0; ks < 3; ++ks)
#pragma unroll
            for (int mm = 0; mm < 4; ++mm)
                acc2[mm][g] = __builtin_amdgcn_mfma_f32_16x16x32_bf16(
                    A2f[((w * 4 + mm) * 3 + ks) * 64 + lane], zf[ks], acc2[mm][g], 0, 0, 0);
    }
    // all z reads done before C staging overwrites the region
    __syncthreads();

    // ---- store: C -> LDS (wave-private slot) -> px-major dwordx4 ----
    float* cw = (float*)xs + w * 32 * CROW;   // aliases region (post-barrier)
#pragma unroll
    for (int p = 0; p < 2; ++p) {
#pragma unroll
        for (int mp = 0; mp < 2; ++mp) {
            const int mm = p * 2 + mp;
#pragma unroll
            for (int g = 0; g < 4; ++g)
#pragma unroll
                for (int r = 0; r < 4; ++r)
                    cw[(mp * 16 + q * 4 + r) * CROW + g * 16 + n] = acc2[mm][g][r];
        }
        // wave-private slot: DS ops from one wave execute in order; no barrier
        const int chs = lane >> 4;            // 0..3
        const int pp = lane & 15;
        float* op = o + (size_t)(w * 64 + p * 32 + chs) * HW + px0 + 4 * pp;
#pragma unroll
        for (int i = 0; i < 8; ++i) {
            float4v v = *(const float4v*)(cw + (i * 4 + chs) * CROW + 4 * pp);
            *(float4v*)(op + (size_t)(i * 4) * HW) = v;   // plain: L2/L3 write-back
        }
    }
}

__global__ __launch_bounds__(256, 4) void fused_v6(
    const float* __restrict__ x0, const float* __restrict__ x1, const float* __restrict__ x2,
    const float* __restrict__ b1_0, const float* __restrict__ b2_0,
    const float* __restrict__ b1_1, const float* __restrict__ b2_1,
    const float* __restrict__ b1_2, const float* __restrict__ b2_2,
    const unsigned short* __restrict__ wpk, float* __restrict__ out)
{
    __shared__ __align__(16) unsigned char smem[SMEM_BYTES];
    unsigned short* xs = (unsigned short*)smem;
    const int bi = (int)blockIdx.x;

    if (bi < 1024) {                        // level 0: 4 batches x 256 tiles
        int b = bi >> 8, px0 = (bi & 255) * 64;
        level3<16384>(x0 + (size_t)b * 256 * 16384, wpk, wpk + 16384, b1_0, b2_0,
                      out + (size_t)b * 256 * 16384, px0, xs);
    } else if (bi < 1280) {                 // level 1: 4 x 64 tiles
        int r = bi - 1024, b = r >> 6, px0 = (r & 63) * 64;
        level3<4096>(x1 + (size_t)b * 256 * 4096, wpk + 40960, wpk + 40960 + 16384,
                     b1_1, b2_1, out + 16777216 + (size_t)b * 256 * 4096, px0, xs);
    } else {                                // level 2: 4 x 16 tiles
        int r = bi - 1280, b = r >> 4, px0 = (r & 15) * 64;
        level3<1024>(x2 + (size_t)b * 256 * 1024, wpk + 81920, wpk + 81920 + 16384,
                     b1_2, b2_2, out + 20971520 + (size_t)b * 256 * 1024, px0, xs);
    }
}

extern "C" void kernel_launch(void* const* d_in, const int* in_sizes, int n_in,
                              void* d_out, int out_size, void* d_ws, size_t ws_size,
                              hipStream_t stream) {
    const float* x0   = (const float*)d_in[0];
    const float* x1   = (const float*)d_in[1];
    const float* x2   = (const float*)d_in[2];
    const float* W1_0 = (const float*)d_in[3];
    const float* b1_0 = (const float*)d_in[4];
    const float* W2_0 = (const float*)d_in[5];
    const float* b2_0 = (const float*)d_in[6];
    const float* W1_1 = (const float*)d_in[7];
    const float* b1_1 = (const float*)d_in[8];
    const float* W2_1 = (const float*)d_in[9];
    const float* b2_1 = (const float*)d_in[10];
    const float* W1_2 = (const float*)d_in[11];
    const float* b1_2 = (const float*)d_in[12];
    const float* W2_2 = (const float*)d_in[13];
    const float* b2_2 = (const float*)d_in[14];
    float* out = (float*)d_out;
    unsigned short* wpk = (unsigned short*)d_ws;   // needs 245760 B

    prepack<<<dim3(480), dim3(256), 0, stream>>>(W1_0, W2_0, W1_1, W2_1, W1_2, W2_2, wpk);
    fused_v6<<<dim3(1344), dim3(256), 0, stream>>>(
        x0, x1, x2, b1_0, b2_0, b1_1, b2_1, b1_2, b2_2, wpk, out);
}

// Round 4
// 191.802 us; speedup vs baseline: 1.0259x; 1.0180x over previous
//
#include <hip/hip_runtime.h>

typedef __attribute__((ext_vector_type(8))) short short8;
typedef __attribute__((ext_vector_type(4))) float float4v;

__device__ __forceinline__ unsigned short f2bf(float f) {
    unsigned u = __float_as_uint(f);
    u = (u + 0x7FFFu + ((u >> 16) & 1u)) >> 16;
    return (unsigned short)u;
}

#define XSET 520    // 512 data + 8 pad ushorts per (g,ks) fragment set
#define CROW2 130   // 128 px + 2 pad floats per staged C row
#define SMEM_BYTES 66688  // x frags (66,656 B) / z frags (25 KB) / C stage (66,560 B)

// ---------------------------------------------------------------------------
// Prepack: W1 [256x64], W2 [96x256] ([cin,cout]) -> bf16 MFMA A-frag order.
// A1: ((mt*8 + ks)*64 + lane)*8 + j   (mt 0..3,  ks 0..7)
// A2: ((mt*3 + ks)*64 + lane)*8 + j   (mt 0..15, ks 0..2)
// ---------------------------------------------------------------------------
__global__ void prepack(const float* __restrict__ W1_0, const float* __restrict__ W2_0,
                        const float* __restrict__ W1_1, const float* __restrict__ W2_1,
                        const float* __restrict__ W1_2, const float* __restrict__ W2_2,
                        unsigned short* __restrict__ ws) {
    int e = blockIdx.x * 256 + threadIdx.x;
    if (e >= 3 * 40960) return;
    int l = e / 40960, r = e % 40960;
    const float* W1 = (l == 0) ? W1_0 : (l == 1) ? W1_1 : W1_2;
    const float* W2 = (l == 0) ? W2_0 : (l == 1) ? W2_1 : W2_2;
    unsigned short* base = ws + l * 40960;
    if (r < 16384) {
        int j = r & 7, lane = (r >> 3) & 63, fs = r >> 9;
        int mt = fs >> 3, ks = fs & 7;
        int k = ks * 32 + (lane >> 4) * 8 + j;
        int m = mt * 16 + (lane & 15);
        base[r] = f2bf(W1[k * 64 + m]);
    } else {
        int r2 = r - 16384;
        int j = r2 & 7, lane = (r2 >> 3) & 63, fs = r2 >> 9;
        int mt = fs / 3, ks = fs - mt * 3;
        int k = ks * 32 + (lane >> 4) * 8 + j;
        int m = mt * 16 + (lane & 15);
        base[16384 + r2] = f2bf(W2[k * 256 + m]);
    }
}

// ---------------------------------------------------------------------------
// v7: 128-px tile per block (was 64). All global runs are 512 B contiguous
// (was 256 B at 64 KB stride -> single-DRAM-granule camping per block, the
// occupancy-/NT-invariant 2.2 TB/s floor of v3..v6). Phase-1 issues 32
// independent dwordx4 loads per thread. LDS (66.7 KB, 2 blocks/CU) is
// time-multiplexed: x frags -> (barrier) -> z frags (aliases x[0..25KB])
// -> (barrier) -> C staging (aliases whole region).
// ---------------------------------------------------------------------------
template<int HW>
__device__ __forceinline__ void level3(
    const float* __restrict__ x,           // this batch: [256][HW]
    const unsigned short* __restrict__ A1,
    const unsigned short* __restrict__ A2,
    const float* __restrict__ b1, const float* __restrict__ b2,
    float* __restrict__ o, int px0,
    unsigned short* __restrict__ xs)
{
    const int t = (int)threadIdx.x;
    const int lane = t & 63, w = t >> 6;
    const int q = lane >> 4, n = lane & 15;
    unsigned short* zs = xs;               // z frags alias x region (barriered)

    // ---- phase 1: stage x [256 ch][128 px] -> bf16 frag layout in LDS ----
    // Per wave-instruction: 2 rows x 512 B contiguous. 32 loads in flight.
    {
        const int pxq = t & 31;            // px = 4*pxq + e
        const int rh  = t >> 5;            // 0..7: ch = rh + 8*i
        const int g = pxq >> 2;            // px group 0..7
        const int n0 = (pxq & 3) * 4;
        const float* xp = x + (size_t)rh * HW + px0 + 4 * pxq;
        float4v v[32];
#pragma unroll
        for (int i = 0; i < 32; ++i)
            v[i] = *(const float4v*)(xp + (size_t)(i * 8) * HW);
#pragma unroll
        for (int i = 0; i < 32; ++i) {
            const int ch = rh + 8 * i;
            const int ks = ch >> 5, qq = (ch >> 3) & 3, j = ch & 7;
            // +g*8 ushort skew vs set base: breaks mod-32-bank degeneracy;
            // 8-ushort set pad absorbs it (verified layout math of v5/v6).
            unsigned short* base = xs + (g * 8 + ks) * XSET + g * 8 + j;
#pragma unroll
            for (int e = 0; e < 4; ++e)
                base[(qq * 16 + n0 + e) * 8] = f2bf(v[i][e]);
        }
    }
    __syncthreads();

    // ---- stage 1: wave w -> px groups g = 2w, 2w+1 ----
    short8 xf[2][8];
#pragma unroll
    for (int u = 0; u < 2; ++u)
#pragma unroll
        for (int ks = 0; ks < 8; ++ks)
            xf[u][ks] = *(const short8*)(xs + ((2 * w + u) * 8 + ks) * XSET
                                            + (2 * w + u) * 8 + lane * 8);
    // all waves must have consumed x frags before z overwrites the region
    __syncthreads();

    float4v acc1[2][4];
#pragma unroll
    for (int u = 0; u < 2; ++u)
#pragma unroll
        for (int mt = 0; mt < 4; ++mt)
            acc1[u][mt] = *(const float4v*)(b1 + mt * 16 + q * 4);

    const short8* A1f = (const short8*)A1;
#pragma unroll
    for (int u = 0; u < 2; ++u)
#pragma unroll
        for (int ks = 0; ks < 8; ++ks)
#pragma unroll
            for (int mt = 0; mt < 4; ++mt)
                acc1[u][mt] = __builtin_amdgcn_mfma_f32_16x16x32_bf16(
                    A1f[(mt * 8 + ks) * 64 + lane], xf[u][ks], acc1[u][mt], 0, 0, 0);

    // ---- z = [y, relu(y_hi)] -> frag-layout LDS (b64 packed), 8 groups ----
#pragma unroll
    for (int u = 0; u < 2; ++u) {
        unsigned short* zg = zs + (2 * w + u) * 3 * XSET;
#pragma unroll
        for (int mt = 0; mt < 4; ++mt) {
            const int kb = mt * 16 + q * 4;
            unsigned long long pk =
                  (unsigned long long)f2bf(acc1[u][mt][0])
                | ((unsigned long long)f2bf(acc1[u][mt][1]) << 16)
                | ((unsigned long long)f2bf(acc1[u][mt][2]) << 32)
                | ((unsigned long long)f2bf(acc1[u][mt][3]) << 48);
            *(unsigned long long*)(zg + (kb >> 5) * XSET +
                (((kb >> 3) & 3) * 16 + n) * 8 + (kb & 7)) = pk;
            if (mt >= 2) {
                const int kr = kb + 32;    // relu copy at k = 64 + (ch-32)
                unsigned long long pr =
                      (unsigned long long)f2bf(fmaxf(acc1[u][mt][0], 0.f))
                    | ((unsigned long long)f2bf(fmaxf(acc1[u][mt][1], 0.f)) << 16)
                    | ((unsigned long long)f2bf(fmaxf(acc1[u][mt][2], 0.f)) << 32)
                    | ((unsigned long long)f2bf(fmaxf(acc1[u][mt][3], 0.f)) << 48);
                *(unsigned long long*)(zg + (kr >> 5) * XSET +
                    (((kr >> 3) & 3) * 16 + n) * 8 + (kr & 7)) = pr;
            }
        }
    }
    __syncthreads();

    // ---- stage 2: wave w -> out-ch 64w..64w+63, all 8 px groups ----
    float4v acc2[4][8];   // [mm][g]  (128 VGPR; launch_bounds(256,2))
#pragma unroll
    for (int mm = 0; mm < 4; ++mm) {
        float4v bb = *(const float4v*)(b2 + (w * 4 + mm) * 16 + q * 4);
#pragma unroll
        for (int g = 0; g < 8; ++g) acc2[mm][g] = bb;
    }

    const short8* A2f = (const short8*)A2;
#pragma unroll
    for (int g = 0; g < 8; ++g) {
        short8 zf[3];
#pragma unroll
        for (int ks = 0; ks < 3; ++ks)
            zf[ks] = *(const short8*)(zs + (g * 3 + ks) * XSET + lane * 8);
#pragma unroll
        for (int ks = 0; ks < 3; ++ks)
#pragma unroll
            for (int mm = 0; mm < 4; ++mm)
                acc2[mm][g] = __builtin_amdgcn_mfma_f32_16x16x32_bf16(
                    A2f[((w * 4 + mm) * 3 + ks) * 64 + lane], zf[ks], acc2[mm][g], 0, 0, 0);
    }
    // all z reads done before C staging overwrites the region
    __syncthreads();

    // ---- store: C -> LDS (wave-private slot) -> px-major 512 B runs ----
    float* cw = (float*)xs + w * 32 * CROW2;
#pragma unroll
    for (int p = 0; p < 2; ++p) {
#pragma unroll
        for (int mp = 0; mp < 2; ++mp) {
            const int mm = p * 2 + mp;
#pragma unroll
            for (int g = 0; g < 8; ++g)
#pragma unroll
                for (int r = 0; r < 4; ++r)
                    cw[(mp * 16 + q * 4 + r) * CROW2 + g * 16 + n] = acc2[mm][g][r];
        }
        // wave-private slot: DS ops from one wave execute in order; no barrier
        const int chs = lane >> 5;         // 0..1
        const int pp = lane & 31;          // px = 4*pp
        float* op = o + (size_t)(w * 64 + p * 32 + chs) * HW + px0 + 4 * pp;
#pragma unroll
        for (int i = 0; i < 16; ++i) {
            float4v v = *(const float4v*)(cw + (2 * i + chs) * CROW2 + 4 * pp);
            *(float4v*)(op + (size_t)(2 * i) * HW) = v;
        }
    }
}

__global__ __launch_bounds__(256, 2) void fused_v7(
    const float* __restrict__ x0, const float* __restrict__ x1, const float* __restrict__ x2,
    const float* __restrict__ b1_0, const float* __restrict__ b2_0,
    const float* __restrict__ b1_1, const float* __restrict__ b2_1,
    const float* __restrict__ b1_2, const float* __restrict__ b2_2,
    const unsigned short* __restrict__ wpk, float* __restrict__ out)
{
    __shared__ __align__(16) unsigned char smem[SMEM_BYTES];
    unsigned short* xs = (unsigned short*)smem;
    const int bi = (int)blockIdx.x;

    if (bi < 512) {                         // level 0: 4 batches x 128 tiles
        int b = bi >> 7, px0 = (bi & 127) * 128;
        level3<16384>(x0 + (size_t)b * 4194304, wpk, wpk + 16384, b1_0, b2_0,
                      out + (size_t)b * 4194304, px0, xs);
    } else if (bi < 640) {                  // level 1: 4 x 32 tiles
        int r = bi - 512, b = r >> 5, px0 = (r & 31) * 128;
        level3<4096>(x1 + (size_t)b * 1048576, wpk + 40960, wpk + 57344,
                     b1_1, b2_1, out + 16777216 + (size_t)b * 1048576, px0, xs);
    } else {                                // level 2: 4 x 8 tiles
        int r = bi - 640, b = r >> 3, px0 = (r & 7) * 128;
        level3<1024>(x2 + (size_t)b * 262144, wpk + 81920, wpk + 98304,
                     b1_2, b2_2, out + 20971520 + (size_t)b * 262144, px0, xs);
    }
}

extern "C" void kernel_launch(void* const* d_in, const int* in_sizes, int n_in,
                              void* d_out, int out_size, void* d_ws, size_t ws_size,
                              hipStream_t stream) {
    const float* x0   = (const float*)d_in[0];
    const float* x1   = (const float*)d_in[1];
    const float* x2   = (const float*)d_in[2];
    const float* W1_0 = (const float*)d_in[3];
    const float* b1_0 = (const float*)d_in[4];
    const float* W2_0 = (const float*)d_in[5];
    const float* b2_0 = (const float*)d_in[6];
    const float* W1_1 = (const float*)d_in[7];
    const float* b1_1 = (const float*)d_in[8];
    const float* W2_1 = (const float*)d_in[9];
    const float* b2_1 = (const float*)d_in[10];
    const float* W1_2 = (const float*)d_in[11];
    const float* b1_2 = (const float*)d_in[12];
    const float* W2_2 = (const float*)d_in[13];
    const float* b2_2 = (const float*)d_in[14];
    float* out = (float*)d_out;
    unsigned short* wpk = (unsigned short*)d_ws;   // needs 245760 B

    prepack<<<dim3(480), dim3(256), 0, stream>>>(W1_0, W2_0, W1_1, W2_1, W1_2, W2_2, wpk);
    fused_v7<<<dim3(672), dim3(256), 0, stream>>>(
        x0, x1, x2, b1_0, b2_0, b1_1, b2_1, b1_2, b2_2, wpk, out);
}